// Round 19
// baseline (698.071 us; speedup 1.0000x reference)
//
#include <hip/hip_runtime.h>
#include <hip/hip_bf16.h>
#include <stdint.h>

// Problem constants: B=2, S=2048, D=2048, H=32, HD=64, 3D=6144, M=B*S=4096, K=2048
typedef unsigned short ushort_t;
typedef __bf16 bf16x8 __attribute__((ext_vector_type(8)));
typedef float f32x4 __attribute__((ext_vector_type(4)));
typedef float f32x16 __attribute__((ext_vector_type(16)));
typedef int int4v __attribute__((ext_vector_type(4)));
typedef ushort_t ushort8 __attribute__((ext_vector_type(8)));

__device__ __forceinline__ ushort_t f2bf(float f) {
  union { float f; unsigned int u; } v; v.f = f;
  unsigned int r = v.u + 0x7fffu + ((v.u >> 16) & 1u);  // RNE
  return (ushort_t)(r >> 16);
}

__device__ __forceinline__ bf16x8 ld_bf8(const ushort_t* p) {
  return *reinterpret_cast<const bf16x8*>(p);
}

__device__ __forceinline__ void g2lds16(const void* g, void* l) {
  __builtin_amdgcn_global_load_lds(
      (const __attribute__((address_space(1))) unsigned int*)g,
      (__attribute__((address_space(3))) unsigned int*)l,
      16, 0, 0);
}

__device__ __forceinline__ float ex2(float x) { return __builtin_amdgcn_exp2f(x); }

// v_cvt_pk_bf16_f32: word = {lo: bf16(a), hi: bf16(b)}
__device__ __forceinline__ int cvtpk(float a, float b) {
  int r;
  asm("v_cvt_pk_bf16_f32 %0, %1, %2" : "=v"(r) : "v"(a), "v"(b));
  return r;
}

// ---------------- Pass 0: fused prep (cvt_hs ++ transpose_W) ----------------
// blocks [0,4096): hidden_states f32 -> bf16 (vectorized copy-cast)
// blocks [4096,7168): W [2048][6144] f32 -> Wt [6144][2048] bf16 (LDS tile)
__global__ __launch_bounds__(256) void prep(const float* __restrict__ hs,
                                            ushort_t* __restrict__ Abf,
                                            const float* __restrict__ Win,
                                            ushort_t* __restrict__ Wt) {
  __shared__ ushort_t T[64][65];
  const int bid = blockIdx.x;
  const int t = threadIdx.x;
  if (bid < 4096) {
    int i = (bid * 256 + t) * 8;
    float4 a = *reinterpret_cast<const float4*>(hs + i);
    float4 b = *reinterpret_cast<const float4*>(hs + i + 4);
    ushort8 r;
    r[0] = f2bf(a.x); r[1] = f2bf(a.y); r[2] = f2bf(a.z); r[3] = f2bf(a.w);
    r[4] = f2bf(b.x); r[5] = f2bf(b.y); r[6] = f2bf(b.z); r[7] = f2bf(b.w);
    *reinterpret_cast<ushort8*>(Abf + i) = r;
  } else {
    const int tb = bid - 4096;
    const int k0 = (tb & 31) * 64;
    const int n0 = (tb >> 5) * 64;
#pragma unroll
    for (int i = 0; i < 16; ++i) {
      int idx = i * 256 + t;
      int r = idx >> 6, c = idx & 63;
      T[r][c] = f2bf(Win[(k0 + r) * 6144 + n0 + c]);
    }
    __syncthreads();
#pragma unroll
    for (int i = 0; i < 16; ++i) {
      int idx = i * 256 + t;
      int nr = idx >> 6, kc = idx & 63;
      Wt[(n0 + nr) * 2048 + k0 + kc] = T[kc][nr];
    }
  }
}

// ---------------- Pass 1: QKV GEMM, head-aligned BN=192, T3-min pipeline ----
// R16-verified structure. __launch_bounds__(256,4): VGPR 88 <= 128 already,
// LDS 4x40960 = 160KiB exactly -> 4 blocks/CU co-resident (grid 1024 = 4/CU).
// Doubled TLP hides the per-iteration barrier drain (m114 wave-overlap).
__global__ __launch_bounds__(256, 4) void gemm_qkv(
    const ushort_t* __restrict__ A, const ushort_t* __restrict__ Bt,
    const float* __restrict__ bias,
    ushort_t* __restrict__ Qb, ushort_t* __restrict__ Kb,
    ushort_t* __restrict__ VT) {
  __shared__ __align__(16) char smem[40960];
  ushort_t* A0 = (ushort_t*)smem;             // [128][32] buf0
  ushort_t* A1 = (ushort_t*)(smem + 8192);    // buf1
  ushort_t* B0 = (ushort_t*)(smem + 16384);   // [192][32] buf0
  ushort_t* B1 = (ushort_t*)(smem + 28672);   // buf1
  ushort_t* Cs = (ushort_t*)smem;             // [64][200] epilogue alias
  const int t = threadIdx.x;
  const int w = t >> 6, l = t & 63;
  const int lo = l & 15, hi = l >> 4;
  const int wr = w >> 1, wc = w & 1;

  int bid = blockIdx.x;
  int swz = (bid & 7) * 128 + (bid >> 3);  // bijective (1024 = 8*128)
  const int mt = swz & 31, nt = swz >> 5;  // 32 x 32 tiles
  const int bm = mt * 128;
  const int bn = nt * 192;

  f32x4 acc[4][6];
#pragma unroll
  for (int i = 0; i < 4; ++i)
#pragma unroll
    for (int j = 0; j < 6; ++j) acc[i][j] = f32x4{0.f, 0.f, 0.f, 0.f};

  const ushort_t* Ag = A + (size_t)bm * 2048;
  const ushort_t* Bg = Bt + (size_t)bn * 2048;

#define STAGE(Ad, Bd, kk_)                                       \
  do {                                                           \
    for (int r2 = 0; r2 < 2; ++r2) {                             \
      int c_ = r2 * 256 + t;                                     \
      int row_ = c_ >> 2, s4_ = c_ & 3;                          \
      int slot_ = s4_ ^ ((row_ & 3) ^ ((row_ >> 2) & 3));        \
      g2lds16(Ag + row_ * 2048 + (kk_) + slot_ * 8, (Ad) + c_ * 8); \
    }                                                            \
    for (int r3 = 0; r3 < 3; ++r3) {                             \
      int c_ = r3 * 256 + t;                                     \
      int row_ = c_ >> 2, s4_ = c_ & 3;                          \
      int slot_ = s4_ ^ ((row_ & 3) ^ ((row_ >> 2) & 3));        \
      g2lds16(Bg + row_ * 2048 + (kk_) + slot_ * 8, (Bd) + c_ * 8); \
    }                                                            \
  } while (0)

  STAGE(A0, B0, 0);
  __syncthreads();
  ushort_t *Ac = A0, *Bc = B0, *An = A1, *Bn = B1;

  for (int kk = 0; kk < 2048; kk += 32) {
    if (kk + 32 < 2048) STAGE(An, Bn, kk + 32);  // issue next-tile loads EARLY
    bf16x8 af[4], bfr[6];
#pragma unroll
    for (int mf = 0; mf < 4; ++mf) {
      int row = wr * 64 + mf * 16 + lo;
      int fr = (row & 3) ^ ((row >> 2) & 3);
      af[mf] = ld_bf8(Ac + row * 32 + ((hi ^ fr) << 3));
    }
#pragma unroll
    for (int nf = 0; nf < 6; ++nf) {
      int row = wc * 96 + nf * 16 + lo;
      int fr = (row & 3) ^ ((row >> 2) & 3);
      bfr[nf] = ld_bf8(Bc + row * 32 + ((hi ^ fr) << 3));
    }
    __builtin_amdgcn_s_setprio(1);
#pragma unroll
    for (int mf = 0; mf < 4; ++mf)
#pragma unroll
      for (int nf = 0; nf < 6; ++nf)
        acc[mf][nf] = __builtin_amdgcn_mfma_f32_16x16x32_bf16(
            af[mf], bfr[nf], acc[mf][nf], 0, 0, 0);
    __builtin_amdgcn_s_setprio(0);
    __syncthreads();  // drains next-buffer vmcnt + fences current-buffer reads
    ushort_t* tmp;
    tmp = Ac; Ac = An; An = tmp;
    tmp = Bc; Bc = Bn; Bn = tmp;
  }
#undef STAGE

  // ---- epilogue: bias + de-interleave via LDS repack, coalesced stores ----
  float bv[6];
  int ch[6];
#pragma unroll
  for (int nf = 0; nf < 6; ++nf) {
    int nl = wc * 96 + nf * 16 + lo;
    bv[nf] = bias[bn + nl];
    ch[nf] = nl % 3;
  }
  const int b_ = bm >> 11;
  const int bh = (b_ << 5) + nt;  // head index == nt
  const float QS = 0.125f * 1.44269504f;

#pragma unroll
  for (int h = 0; h < 2; ++h) {
    if (wr == h) {
#pragma unroll
      for (int mf = 0; mf < 4; ++mf)
#pragma unroll
        for (int nf = 0; nf < 6; ++nf) {
          int rloc = mf * 16 + hi * 4;
          int nl = wc * 96 + nf * 16 + lo;
          f32x4 a = acc[mf][nf];
#pragma unroll
          for (int j = 0; j < 4; ++j) {
            float v = a[j] + bv[nf];
            if (ch[nf] == 0) v *= QS;
            Cs[(rloc + j) * 200 + nl] = f2bf(v);
          }
        }
    }
    __syncthreads();
    const int sbase = (bm & 2047) + h * 64;
#pragma unroll
    for (int it = 0; it < 2; ++it) {
      int slot = it * 256 + t;
      int r = slot >> 3, g = slot & 7;
      ushort8 vq, vk;
#pragma unroll
      for (int u = 0; u < 8; ++u) {
        int hd = g * 8 + u;
        vq[u] = Cs[r * 200 + hd * 3];
        vk[u] = Cs[r * 200 + hd * 3 + 2];
      }
      size_t rowoff = ((size_t)bh * 2048 + sbase + r) * 64 + g * 8;
      *reinterpret_cast<ushort8*>(Qb + rowoff) = vq;
      *reinterpret_cast<ushort8*>(Kb + rowoff) = vk;
    }
#pragma unroll
    for (int it = 0; it < 2; ++it) {
      int slot = it * 256 + t;
      int hd = slot >> 3, sg = slot & 7;
      ushort8 vv;
#pragma unroll
      for (int u = 0; u < 8; ++u) vv[u] = Cs[(sg * 8 + u) * 200 + hd * 3 + 1];
      *reinterpret_cast<ushort8*>(VT + ((size_t)bh * 64 + hd) * 2048 + sbase +
                                  sg * 8) = vv;
    }
    __syncthreads();
  }
}

// ---------------- attn helpers (R14-verified math, byte-identical) ----------
__device__ __forceinline__ void ldkv(const ushort_t* kp, const ushort_t* vp,
                                     bf16x8 k[4], bf16x8 v0[2], bf16x8 v1[2]) {
#pragma unroll
  for (int dc = 0; dc < 4; ++dc) k[dc] = ld_bf8(kp + dc * 16);
#pragma unroll
  for (int s = 0; s < 2; ++s) {
    v0[s] = ld_bf8(vp + s * 16);
    v1[s] = ld_bf8(vp + s * 16 + 32 * 2048);
  }
}

__device__ __forceinline__ void proc_chunk(const bf16x8 kf[4],
                                           const bf16x8 vf0[2],
                                           const bf16x8 vf1[2],
                                           const bf16x8 qf[4], f32x16& o0,
                                           f32x16& o1, float& mr, float& lr,
                                           bool diag, int ql, int hi) {
  f32x16 p;
#pragma unroll
  for (int r = 0; r < 16; ++r) p[r] = 0.f;
  __builtin_amdgcn_s_setprio(1);
#pragma unroll
  for (int dc = 0; dc < 4; ++dc)
    p = __builtin_amdgcn_mfma_f32_32x32x16_bf16(kf[dc], qf[dc], p, 0, 0, 0);
  __builtin_amdgcn_s_setprio(0);
  if (diag) {  // diagonal chunk: mask kv > q
#pragma unroll
    for (int r = 0; r < 16; ++r) {
      int kvr = (r & 3) + 8 * (r >> 2) + 4 * hi;
      if (kvr > ql) p[r] = -1e30f;
    }
  }
  // own-half pairwise-tree max (no cross-half exchange in common path)
  float a0 = fmaxf(p[0], p[1]), a1 = fmaxf(p[2], p[3]);
  float a2 = fmaxf(p[4], p[5]), a3 = fmaxf(p[6], p[7]);
  float a4 = fmaxf(p[8], p[9]), a5 = fmaxf(p[10], p[11]);
  float a6 = fmaxf(p[12], p[13]), a7 = fmaxf(p[14], p[15]);
  float mx = fmaxf(fmaxf(fmaxf(a0, a1), fmaxf(a2, a3)),
                   fmaxf(fmaxf(a4, a5), fmaxf(a6, a7)));
  // defer-max: __any spans all 64 lanes -> own-half mx gives identical
  // wave-wide trigger; exchange only inside the (wave-uniform) branch.
  if (__any(mx > mr + 10.0f)) {
    mx = fmaxf(mx, __shfl_xor(mx, 32));
    float mn = fmaxf(mr, mx);
    float scl = ex2(mr - mn);
    mr = mn;
    lr *= scl;
#pragma unroll
    for (int r = 0; r < 16; ++r) { o0[r] *= scl; o1[r] *= scl; }
  }
#pragma unroll
  for (int r = 0; r < 16; ++r) p[r] = ex2(p[r] - mr);
  float s0 = (p[0] + p[1]) + (p[2] + p[3]);
  float s1 = (p[4] + p[5]) + (p[6] + p[7]);
  float s2 = (p[8] + p[9]) + (p[10] + p[11]);
  float s3 = (p[12] + p[13]) + (p[14] + p[15]);
  lr += (s0 + s1) + (s2 + s3);  // own-half partial; merged in epilogue

  // P^T -> bf16 B-fragments, in-register (cvt_pk + lane^32 shfl exchange)
  __builtin_amdgcn_s_setprio(1);
#pragma unroll
  for (int s = 0; s < 2; ++s) {
    int x0 = cvtpk(p[8 * s + 0], p[8 * s + 1]);
    int x1 = cvtpk(p[8 * s + 2], p[8 * s + 3]);
    int y0 = cvtpk(p[8 * s + 4], p[8 * s + 5]);
    int y1 = cvtpk(p[8 * s + 6], p[8 * s + 7]);
    int ox0 = __shfl_xor(x0, 32);
    int ox1 = __shfl_xor(x1, 32);
    int oy0 = __shfl_xor(y0, 32);
    int oy1 = __shfl_xor(y1, 32);
    int4v wv;
    wv[0] = hi ? oy0 : x0;
    wv[1] = hi ? oy1 : x1;
    wv[2] = hi ? y0 : ox0;
    wv[3] = hi ? y1 : ox1;
    bf16x8 pf = __builtin_bit_cast(bf16x8, wv);
    o0 = __builtin_amdgcn_mfma_f32_32x32x16_bf16(vf0[s], pf, o0, 0, 0, 0);
    o1 = __builtin_amdgcn_mfma_f32_32x32x16_bf16(vf1[s], pf, o1, 0, 0, 0);
  }
  __builtin_amdgcn_s_setprio(0);
}

// ---------------- Pass 2: attention, CONCURRENT paired q-tiles --------------
// (R16-verified winner, unchanged) grid = 2048 one-wave blocks; tile A (qt=p)
// and tile B (qt=63-p) processed concurrently over one shared K/V stream.
__global__ __launch_bounds__(64) void attn(
    const ushort_t* __restrict__ Qb, const ushort_t* __restrict__ Kb,
    const ushort_t* __restrict__ VT, float* __restrict__ out) {
  __shared__ float Ld[32 * 66];  // 8448 B, wave-private
  const int l = threadIdx.x;
  const int ql = l & 31, hi = l >> 5;

  const int bid = blockIdx.x;
  const int bh = bid & 63;   // one bh per CU (L2 locality)
  const int p = bid >> 6;    // pair index 0..31
  const int nchB = 64 - p;   // tile B (qt=63-p) chunk count; A needs c<=p
  const int q0A = p * 32;
  const int q0B = (63 - p) * 32;
  const int b_ = bh >> 5, h = bh & 31;

  const ushort_t* kbase = Kb + bh * 2048 * 64 + hi * 8;
  const ushort_t* vbase = VT + (bh * 64 + ql) * 2048 + hi * 8;
  const int KSTR = 32 * 64;  // K row-stride per chunk (elements)
  const int VSTR = 32;       // V col-stride per chunk

  bf16x8 qfA[4], qfB[4];
  {
    const ushort_t* qpA = Qb + (bh * 2048 + q0A + ql) * 64 + hi * 8;
    const ushort_t* qpB = Qb + (bh * 2048 + q0B + ql) * 64 + hi * 8;
#pragma unroll
    for (int dc = 0; dc < 4; ++dc) {
      qfA[dc] = ld_bf8(qpA + dc * 16);
      qfB[dc] = ld_bf8(qpB + dc * 16);
    }
  }

  f32x16 oA0, oA1, oB0, oB1;
#pragma unroll
  for (int r = 0; r < 16; ++r) {
    oA0[r] = 0.f; oA1[r] = 0.f; oB0[r] = 0.f; oB1[r] = 0.f;
  }
  float mA = -1e30f, lA = 0.f, mB = -1e30f, lB = 0.f;

  bf16x8 kX[4], vX0[2], vX1[2], kY[4], vY0[2], vY1[2];
  const ushort_t* kp = kbase + ql * 64;
  const ushort_t* vp = vbase;
  ldkv(kp, vp, kX, vX0, vX1);  // chunk 0 -> X

  int c = 0;
  while (c + 2 <= nchB) {
    kp += KSTR; vp += VSTR;
    ldkv(kp, vp, kY, vY0, vY1);  // chunk c+1 -> Y (issued before compute)
    proc_chunk(kX, vX0, vX1, qfB, oB0, oB1, mB, lB, false, ql, hi);
    if (c <= p)
      proc_chunk(kX, vX0, vX1, qfA, oA0, oA1, mA, lA, (c == p), ql, hi);
    if (c + 2 < nchB) {
      kp += KSTR; vp += VSTR;
      ldkv(kp, vp, kX, vX0, vX1);  // chunk c+2 -> X
    }
    proc_chunk(kY, vY0, vY1, qfB, oB0, oB1, mB, lB, (c + 1 == nchB - 1), ql,
               hi);
    if (c + 1 <= p)
      proc_chunk(kY, vY0, vY1, qfA, oA0, oA1, mA, lA, (c + 1 == p), ql, hi);
    c += 2;
  }
  if (c < nchB) {  // odd remainder: final chunk (B diagonal) in X
    proc_chunk(kX, vX0, vX1, qfB, oB0, oB1, mB, lB, true, ql, hi);
    if (c <= p)
      proc_chunk(kX, vX0, vX1, qfA, oA0, oA1, mA, lA, (c == p), ql, hi);
  }

  // epilogue tile A then tile B (shared Ld; 1-wave block, barriers cheap)
#pragma unroll 1
  for (int tile = 0; tile < 2; ++tile) {
    const float lr = tile ? lB : lA;
    const float lrf = lr + __shfl_xor(lr, 32);
    const float inv = 1.0f / lrf;
    const int q0 = tile ? q0B : q0A;
#pragma unroll
    for (int r = 0; r < 16; ++r) {
      int hdv = (r & 3) + 8 * (r >> 2) + 4 * hi;
      Ld[ql * 66 + hdv] = (tile ? oB0[r] : oA0[r]) * inv;
      Ld[ql * 66 + 32 + hdv] = (tile ? oB1[r] : oA1[r]) * inv;
    }
    __syncthreads();
    float* op = out + (size_t)(b_ * 2048 + q0) * 2048 + h * 64 + l;
#pragma unroll
    for (int i = 0; i < 32; ++i) {
      op[(size_t)i * 2048] = Ld[i * 66 + l];
    }
    __syncthreads();
  }
}

// ---------------------------------------------------------------------------
extern "C" void kernel_launch(void* const* d_in, const int* in_sizes, int n_in,
                              void* d_out, int out_size, void* d_ws,
                              size_t ws_size, hipStream_t stream) {
  (void)in_sizes; (void)n_in; (void)out_size; (void)ws_size;
  const float* hs = (const float*)d_in[0];    // [2,2048,2048]
  const float* W = (const float*)d_in[1];     // [2048,6144]
  const float* bias = (const float*)d_in[2];  // [6144]
  float* out = (float*)d_out;

  char* ws = (char*)d_ws;
  ushort_t* Abf = (ushort_t*)(ws);                        // 16 MiB  [4096][2048]
  ushort_t* Wt = (ushort_t*)(ws + (16u << 20));           // 24 MiB  [6144][2048]
  ushort_t* Qb = (ushort_t*)(ws + (40u << 20));           // 16 MiB  [64][2048][64]
  ushort_t* Kb = (ushort_t*)(ws + (56u << 20));           // 16 MiB  [64][2048][64]
  ushort_t* VT = (ushort_t*)(ws + (72u << 20));           // 16 MiB  [64][64][2048]

  hipLaunchKernelGGL(prep, dim3(7168), dim3(256), 0, stream, hs, Abf, W, Wt);
  hipLaunchKernelGGL(gemm_qkv, dim3(1024), dim3(256), 0, stream, Abf, Wt, bias,
                     Qb, Kb, VT);
  hipLaunchKernelGGL(attn, dim3(2048), dim3(64), 0, stream, Qb, Kb, VT, out);
}

// Round 20
// 234.212 us; speedup vs baseline: 2.9805x; 2.9805x over previous
//
#include <hip/hip_runtime.h>
#include <hip/hip_bf16.h>
#include <stdint.h>

// Problem constants: B=2, S=2048, D=2048, H=32, HD=64, 3D=6144, M=B*S=4096, K=2048
typedef unsigned short ushort_t;
typedef __bf16 bf16x8 __attribute__((ext_vector_type(8)));
typedef float f32x4 __attribute__((ext_vector_type(4)));
typedef float f32x16 __attribute__((ext_vector_type(16)));
typedef int int4v __attribute__((ext_vector_type(4)));
typedef ushort_t ushort8 __attribute__((ext_vector_type(8)));

__device__ __forceinline__ ushort_t f2bf(float f) {
  union { float f; unsigned int u; } v; v.f = f;
  unsigned int r = v.u + 0x7fffu + ((v.u >> 16) & 1u);  // RNE
  return (ushort_t)(r >> 16);
}

__device__ __forceinline__ bf16x8 ld_bf8(const ushort_t* p) {
  return *reinterpret_cast<const bf16x8*>(p);
}

__device__ __forceinline__ void g2lds16(const void* g, void* l) {
  __builtin_amdgcn_global_load_lds(
      (const __attribute__((address_space(1))) unsigned int*)g,
      (__attribute__((address_space(3))) unsigned int*)l,
      16, 0, 0);
}

__device__ __forceinline__ float ex2(float x) { return __builtin_amdgcn_exp2f(x); }

// v_cvt_pk_bf16_f32: word = {lo: bf16(a), hi: bf16(b)}
__device__ __forceinline__ int cvtpk(float a, float b) {
  int r;
  asm("v_cvt_pk_bf16_f32 %0, %1, %2" : "=v"(r) : "v"(a), "v"(b));
  return r;
}

// ---------------- Pass 0: fused prep (cvt_hs ++ transpose_W) ----------------
__global__ __launch_bounds__(256) void prep(const float* __restrict__ hs,
                                            ushort_t* __restrict__ Abf,
                                            const float* __restrict__ Win,
                                            ushort_t* __restrict__ Wt) {
  __shared__ ushort_t T[64][65];
  const int bid = blockIdx.x;
  const int t = threadIdx.x;
  if (bid < 4096) {
    int i = (bid * 256 + t) * 8;
    float4 a = *reinterpret_cast<const float4*>(hs + i);
    float4 b = *reinterpret_cast<const float4*>(hs + i + 4);
    ushort8 r;
    r[0] = f2bf(a.x); r[1] = f2bf(a.y); r[2] = f2bf(a.z); r[3] = f2bf(a.w);
    r[4] = f2bf(b.x); r[5] = f2bf(b.y); r[6] = f2bf(b.z); r[7] = f2bf(b.w);
    *reinterpret_cast<ushort8*>(Abf + i) = r;
  } else {
    const int tb = bid - 4096;
    const int k0 = (tb & 31) * 64;
    const int n0 = (tb >> 5) * 64;
#pragma unroll
    for (int i = 0; i < 16; ++i) {
      int idx = i * 256 + t;
      int r = idx >> 6, c = idx & 63;
      T[r][c] = f2bf(Win[(k0 + r) * 6144 + n0 + c]);
    }
    __syncthreads();
#pragma unroll
    for (int i = 0; i < 16; ++i) {
      int idx = i * 256 + t;
      int nr = idx >> 6, kc = idx & 63;
      Wt[(n0 + nr) * 2048 + k0 + kc] = T[kc][nr];
    }
  }
}

// ---------------- Pass 1: QKV GEMM, head-aligned BN=192, BK=64 pipeline -----
// R16-verified T3-min structure with BK doubled to 64: one STAGE (10 loads) +
// two 32-col half-computes + ONE barrier per 64-K step (barriers halved,
// drain amortized 2x). Frag registers reused per half -> pressure unchanged.
// LDS 2x(16K+24K) = 80KB -> exactly 2 blocks/CU (register-bound anyway:
// unified VGPR+AGPR ~184/wave; NEVER bound min-waves higher — R13/R19).
__global__ __launch_bounds__(256, 2) void gemm_qkv(
    const ushort_t* __restrict__ A, const ushort_t* __restrict__ Bt,
    const float* __restrict__ bias,
    ushort_t* __restrict__ Qb, ushort_t* __restrict__ Kb,
    ushort_t* __restrict__ VT) {
  __shared__ __align__(16) char smem[81920];
  ushort_t* A0 = (ushort_t*)smem;              // [128][64] buf0 (16KB)
  ushort_t* A1 = (ushort_t*)(smem + 16384);    // buf1
  ushort_t* B0 = (ushort_t*)(smem + 32768);    // [192][64] buf0 (24KB)
  ushort_t* B1 = (ushort_t*)(smem + 57344);    // buf1
  ushort_t* Cs = (ushort_t*)smem;              // [64][200] epilogue alias
  const int t = threadIdx.x;
  const int w = t >> 6, l = t & 63;
  const int lo = l & 15, hi = l >> 4;
  const int wr = w >> 1, wc = w & 1;

  int bid = blockIdx.x;
  int swz = (bid & 7) * 128 + (bid >> 3);  // bijective (1024 = 8*128)
  const int mt = swz & 31, nt = swz >> 5;  // 32 x 32 tiles
  const int bm = mt * 128;
  const int bn = nt * 192;

  f32x4 acc[4][6];
#pragma unroll
  for (int i = 0; i < 4; ++i)
#pragma unroll
    for (int j = 0; j < 6; ++j) acc[i][j] = f32x4{0.f, 0.f, 0.f, 0.f};

  const ushort_t* Ag = A + (size_t)bm * 2048;
  const ushort_t* Bg = Bt + (size_t)bn * 2048;

  // STAGE one BK=64 tile: A 128x64 (4 iters), B 192x64 (6 iters).
  // idx -> row = idx>>3, s8 = idx&7, half = s8>>2, s4 = s8&3;
  // source col = kk + half*32 + (s4 ^ f(row))*8; dest linear idx*16B.
#define STAGE(Ad, Bd, kk_)                                            \
  do {                                                                \
    for (int r4 = 0; r4 < 4; ++r4) {                                  \
      int c_ = r4 * 256 + t;                                          \
      int row_ = c_ >> 3, s8_ = c_ & 7;                               \
      int half_ = s8_ >> 2, s4_ = s8_ & 3;                            \
      int slot_ = s4_ ^ ((row_ & 3) ^ ((row_ >> 2) & 3));             \
      g2lds16(Ag + row_ * 2048 + (kk_) + half_ * 32 + slot_ * 8,      \
              (Ad) + c_ * 8);                                         \
    }                                                                 \
    for (int r6 = 0; r6 < 6; ++r6) {                                  \
      int c_ = r6 * 256 + t;                                          \
      int row_ = c_ >> 3, s8_ = c_ & 7;                               \
      int half_ = s8_ >> 2, s4_ = s8_ & 3;                            \
      int slot_ = s4_ ^ ((row_ & 3) ^ ((row_ >> 2) & 3));             \
      g2lds16(Bg + row_ * 2048 + (kk_) + half_ * 32 + slot_ * 8,      \
              (Bd) + c_ * 8);                                         \
    }                                                                 \
  } while (0)

  STAGE(A0, B0, 0);
  __syncthreads();
  ushort_t *Ac = A0, *Bc = B0, *An = A1, *Bn = B1;

  for (int kk = 0; kk < 2048; kk += 64) {
    if (kk + 64 < 2048) STAGE(An, Bn, kk + 64);  // issue next-tile loads EARLY
#pragma unroll
    for (int ko = 0; ko < 64; ko += 32) {  // two half-computes, regs reused
      bf16x8 af[4], bfr[6];
#pragma unroll
      for (int mf = 0; mf < 4; ++mf) {
        int row = wr * 64 + mf * 16 + lo;
        int fr = (row & 3) ^ ((row >> 2) & 3);
        af[mf] = ld_bf8(Ac + row * 64 + ko + ((hi ^ fr) << 3));
      }
#pragma unroll
      for (int nf = 0; nf < 6; ++nf) {
        int row = wc * 96 + nf * 16 + lo;
        int fr = (row & 3) ^ ((row >> 2) & 3);
        bfr[nf] = ld_bf8(Bc + row * 64 + ko + ((hi ^ fr) << 3));
      }
      __builtin_amdgcn_s_setprio(1);
#pragma unroll
      for (int mf = 0; mf < 4; ++mf)
#pragma unroll
        for (int nf = 0; nf < 6; ++nf)
          acc[mf][nf] = __builtin_amdgcn_mfma_f32_16x16x32_bf16(
              af[mf], bfr[nf], acc[mf][nf], 0, 0, 0);
      __builtin_amdgcn_s_setprio(0);
    }
    __syncthreads();  // drains next-buffer vmcnt + fences current-buffer reads
    ushort_t* tmp;
    tmp = Ac; Ac = An; An = tmp;
    tmp = Bc; Bc = Bn; Bn = tmp;
  }
#undef STAGE

  // ---- epilogue: bias + de-interleave via LDS repack, coalesced stores ----
  float bv[6];
  int ch[6];
#pragma unroll
  for (int nf = 0; nf < 6; ++nf) {
    int nl = wc * 96 + nf * 16 + lo;
    bv[nf] = bias[bn + nl];
    ch[nf] = nl % 3;
  }
  const int b_ = bm >> 11;
  const int bh = (b_ << 5) + nt;  // head index == nt
  const float QS = 0.125f * 1.44269504f;

#pragma unroll
  for (int h = 0; h < 2; ++h) {
    if (wr == h) {
#pragma unroll
      for (int mf = 0; mf < 4; ++mf)
#pragma unroll
        for (int nf = 0; nf < 6; ++nf) {
          int rloc = mf * 16 + hi * 4;
          int nl = wc * 96 + nf * 16 + lo;
          f32x4 a = acc[mf][nf];
#pragma unroll
          for (int j = 0; j < 4; ++j) {
            float v = a[j] + bv[nf];
            if (ch[nf] == 0) v *= QS;
            Cs[(rloc + j) * 200 + nl] = f2bf(v);
          }
        }
    }
    __syncthreads();
    const int sbase = (bm & 2047) + h * 64;
#pragma unroll
    for (int it = 0; it < 2; ++it) {
      int slot = it * 256 + t;
      int r = slot >> 3, g = slot & 7;
      ushort8 vq, vk;
#pragma unroll
      for (int u = 0; u < 8; ++u) {
        int hd = g * 8 + u;
        vq[u] = Cs[r * 200 + hd * 3];
        vk[u] = Cs[r * 200 + hd * 3 + 2];
      }
      size_t rowoff = ((size_t)bh * 2048 + sbase + r) * 64 + g * 8;
      *reinterpret_cast<ushort8*>(Qb + rowoff) = vq;
      *reinterpret_cast<ushort8*>(Kb + rowoff) = vk;
    }
#pragma unroll
    for (int it = 0; it < 2; ++it) {
      int slot = it * 256 + t;
      int hd = slot >> 3, sg = slot & 7;
      ushort8 vv;
#pragma unroll
      for (int u = 0; u < 8; ++u) vv[u] = Cs[(sg * 8 + u) * 200 + hd * 3 + 1];
      *reinterpret_cast<ushort8*>(VT + ((size_t)bh * 64 + hd) * 2048 + sbase +
                                  sg * 8) = vv;
    }
    __syncthreads();
  }
}

// ---------------- attn helpers (R14-verified math, byte-identical) ----------
__device__ __forceinline__ void ldkv(const ushort_t* kp, const ushort_t* vp,
                                     bf16x8 k[4], bf16x8 v0[2], bf16x8 v1[2]) {
#pragma unroll
  for (int dc = 0; dc < 4; ++dc) k[dc] = ld_bf8(kp + dc * 16);
#pragma unroll
  for (int s = 0; s < 2; ++s) {
    v0[s] = ld_bf8(vp + s * 16);
    v1[s] = ld_bf8(vp + s * 16 + 32 * 2048);
  }
}

__device__ __forceinline__ void proc_chunk(const bf16x8 kf[4],
                                           const bf16x8 vf0[2],
                                           const bf16x8 vf1[2],
                                           const bf16x8 qf[4], f32x16& o0,
                                           f32x16& o1, float& mr, float& lr,
                                           bool diag, int ql, int hi) {
  f32x16 p;
#pragma unroll
  for (int r = 0; r < 16; ++r) p[r] = 0.f;
  __builtin_amdgcn_s_setprio(1);
#pragma unroll
  for (int dc = 0; dc < 4; ++dc)
    p = __builtin_amdgcn_mfma_f32_32x32x16_bf16(kf[dc], qf[dc], p, 0, 0, 0);
  __builtin_amdgcn_s_setprio(0);
  if (diag) {  // diagonal chunk: mask kv > q
#pragma unroll
    for (int r = 0; r < 16; ++r) {
      int kvr = (r & 3) + 8 * (r >> 2) + 4 * hi;
      if (kvr > ql) p[r] = -1e30f;
    }
  }
  // own-half pairwise-tree max (no cross-half exchange in common path)
  float a0 = fmaxf(p[0], p[1]), a1 = fmaxf(p[2], p[3]);
  float a2 = fmaxf(p[4], p[5]), a3 = fmaxf(p[6], p[7]);
  float a4 = fmaxf(p[8], p[9]), a5 = fmaxf(p[10], p[11]);
  float a6 = fmaxf(p[12], p[13]), a7 = fmaxf(p[14], p[15]);
  float mx = fmaxf(fmaxf(fmaxf(a0, a1), fmaxf(a2, a3)),
                   fmaxf(fmaxf(a4, a5), fmaxf(a6, a7)));
  // defer-max: __any spans all 64 lanes -> own-half mx gives identical
  // wave-wide trigger; exchange only inside the (wave-uniform) branch.
  if (__any(mx > mr + 10.0f)) {
    mx = fmaxf(mx, __shfl_xor(mx, 32));
    float mn = fmaxf(mr, mx);
    float scl = ex2(mr - mn);
    mr = mn;
    lr *= scl;
#pragma unroll
    for (int r = 0; r < 16; ++r) { o0[r] *= scl; o1[r] *= scl; }
  }
#pragma unroll
  for (int r = 0; r < 16; ++r) p[r] = ex2(p[r] - mr);
  float s0 = (p[0] + p[1]) + (p[2] + p[3]);
  float s1 = (p[4] + p[5]) + (p[6] + p[7]);
  float s2 = (p[8] + p[9]) + (p[10] + p[11]);
  float s3 = (p[12] + p[13]) + (p[14] + p[15]);
  lr += (s0 + s1) + (s2 + s3);  // own-half partial; merged in epilogue

  // P^T -> bf16 B-fragments, in-register (cvt_pk + lane^32 shfl exchange)
  __builtin_amdgcn_s_setprio(1);
#pragma unroll
  for (int s = 0; s < 2; ++s) {
    int x0 = cvtpk(p[8 * s + 0], p[8 * s + 1]);
    int x1 = cvtpk(p[8 * s + 2], p[8 * s + 3]);
    int y0 = cvtpk(p[8 * s + 4], p[8 * s + 5]);
    int y1 = cvtpk(p[8 * s + 6], p[8 * s + 7]);
    int ox0 = __shfl_xor(x0, 32);
    int ox1 = __shfl_xor(x1, 32);
    int oy0 = __shfl_xor(y0, 32);
    int oy1 = __shfl_xor(y1, 32);
    int4v wv;
    wv[0] = hi ? oy0 : x0;
    wv[1] = hi ? oy1 : x1;
    wv[2] = hi ? y0 : ox0;
    wv[3] = hi ? y1 : ox1;
    bf16x8 pf = __builtin_bit_cast(bf16x8, wv);
    o0 = __builtin_amdgcn_mfma_f32_32x32x16_bf16(vf0[s], pf, o0, 0, 0, 0);
    o1 = __builtin_amdgcn_mfma_f32_32x32x16_bf16(vf1[s], pf, o1, 0, 0, 0);
  }
  __builtin_amdgcn_s_setprio(0);
}

// ---------------- Pass 2: attention, CONCURRENT paired q-tiles --------------
// (R16-verified winner, unchanged) grid = 2048 one-wave blocks; tile A (qt=p)
// and tile B (qt=63-p) processed concurrently over one shared K/V stream.
__global__ __launch_bounds__(64) void attn(
    const ushort_t* __restrict__ Qb, const ushort_t* __restrict__ Kb,
    const ushort_t* __restrict__ VT, float* __restrict__ out) {
  __shared__ float Ld[32 * 66];  // 8448 B, wave-private
  const int l = threadIdx.x;
  const int ql = l & 31, hi = l >> 5;

  const int bid = blockIdx.x;
  const int bh = bid & 63;   // one bh per CU (L2 locality)
  const int p = bid >> 6;    // pair index 0..31
  const int nchB = 64 - p;   // tile B (qt=63-p) chunk count; A needs c<=p
  const int q0A = p * 32;
  const int q0B = (63 - p) * 32;
  const int b_ = bh >> 5, h = bh & 31;

  const ushort_t* kbase = Kb + bh * 2048 * 64 + hi * 8;
  const ushort_t* vbase = VT + (bh * 64 + ql) * 2048 + hi * 8;
  const int KSTR = 32 * 64;  // K row-stride per chunk (elements)
  const int VSTR = 32;       // V col-stride per chunk

  bf16x8 qfA[4], qfB[4];
  {
    const ushort_t* qpA = Qb + (bh * 2048 + q0A + ql) * 64 + hi * 8;
    const ushort_t* qpB = Qb + (bh * 2048 + q0B + ql) * 64 + hi * 8;
#pragma unroll
    for (int dc = 0; dc < 4; ++dc) {
      qfA[dc] = ld_bf8(qpA + dc * 16);
      qfB[dc] = ld_bf8(qpB + dc * 16);
    }
  }

  f32x16 oA0, oA1, oB0, oB1;
#pragma unroll
  for (int r = 0; r < 16; ++r) {
    oA0[r] = 0.f; oA1[r] = 0.f; oB0[r] = 0.f; oB1[r] = 0.f;
  }
  float mA = -1e30f, lA = 0.f, mB = -1e30f, lB = 0.f;

  bf16x8 kX[4], vX0[2], vX1[2], kY[4], vY0[2], vY1[2];
  const ushort_t* kp = kbase + ql * 64;
  const ushort_t* vp = vbase;
  ldkv(kp, vp, kX, vX0, vX1);  // chunk 0 -> X

  int c = 0;
  while (c + 2 <= nchB) {
    kp += KSTR; vp += VSTR;
    ldkv(kp, vp, kY, vY0, vY1);  // chunk c+1 -> Y (issued before compute)
    proc_chunk(kX, vX0, vX1, qfB, oB0, oB1, mB, lB, false, ql, hi);
    if (c <= p)
      proc_chunk(kX, vX0, vX1, qfA, oA0, oA1, mA, lA, (c == p), ql, hi);
    if (c + 2 < nchB) {
      kp += KSTR; vp += VSTR;
      ldkv(kp, vp, kX, vX0, vX1);  // chunk c+2 -> X
    }
    proc_chunk(kY, vY0, vY1, qfB, oB0, oB1, mB, lB, (c + 1 == nchB - 1), ql,
               hi);
    if (c + 1 <= p)
      proc_chunk(kY, vY0, vY1, qfA, oA0, oA1, mA, lA, (c + 1 == p), ql, hi);
    c += 2;
  }
  if (c < nchB) {  // odd remainder: final chunk (B diagonal) in X
    proc_chunk(kX, vX0, vX1, qfB, oB0, oB1, mB, lB, true, ql, hi);
    if (c <= p)
      proc_chunk(kX, vX0, vX1, qfA, oA0, oA1, mA, lA, (c == p), ql, hi);
  }

  // epilogue tile A then tile B (shared Ld; 1-wave block, barriers cheap)
#pragma unroll 1
  for (int tile = 0; tile < 2; ++tile) {
    const float lr = tile ? lB : lA;
    const float lrf = lr + __shfl_xor(lr, 32);
    const float inv = 1.0f / lrf;
    const int q0 = tile ? q0B : q0A;
#pragma unroll
    for (int r = 0; r < 16; ++r) {
      int hdv = (r & 3) + 8 * (r >> 2) + 4 * hi;
      Ld[ql * 66 + hdv] = (tile ? oB0[r] : oA0[r]) * inv;
      Ld[ql * 66 + 32 + hdv] = (tile ? oB1[r] : oA1[r]) * inv;
    }
    __syncthreads();
    float* op = out + (size_t)(b_ * 2048 + q0) * 2048 + h * 64 + l;
#pragma unroll
    for (int i = 0; i < 32; ++i) {
      op[(size_t)i * 2048] = Ld[i * 66 + l];
    }
    __syncthreads();
  }
}

// ---------------------------------------------------------------------------
extern "C" void kernel_launch(void* const* d_in, const int* in_sizes, int n_in,
                              void* d_out, int out_size, void* d_ws,
                              size_t ws_size, hipStream_t stream) {
  (void)in_sizes; (void)n_in; (void)out_size; (void)ws_size;
  const float* hs = (const float*)d_in[0];    // [2,2048,2048]
  const float* W = (const float*)d_in[1];     // [2048,6144]
  const float* bias = (const float*)d_in[2];  // [6144]
  float* out = (float*)d_out;

  char* ws = (char*)d_ws;
  ushort_t* Abf = (ushort_t*)(ws);                        // 16 MiB  [4096][2048]
  ushort_t* Wt = (ushort_t*)(ws + (16u << 20));           // 24 MiB  [6144][2048]
  ushort_t* Qb = (ushort_t*)(ws + (40u << 20));           // 16 MiB  [64][2048][64]
  ushort_t* Kb = (ushort_t*)(ws + (56u << 20));           // 16 MiB  [64][2048][64]
  ushort_t* VT = (ushort_t*)(ws + (72u << 20));           // 16 MiB  [64][64][2048]

  hipLaunchKernelGGL(prep, dim3(7168), dim3(256), 0, stream, hs, Abf, W, Wt);
  hipLaunchKernelGGL(gemm_qkv, dim3(1024), dim3(256), 0, stream, Abf, Wt, bias,
                     Qb, Kb, VT);
  hipLaunchKernelGGL(attn, dim3(2048), dim3(64), 0, stream, Qb, Kb, VT, out);
}